// Round 2
// baseline (603.378 us; speedup 1.0000x reference)
//
#include <hip/hip_runtime.h>
#include <hip/hip_bf16.h>

typedef __hip_bfloat16 bf16;
typedef short short8 __attribute__((ext_vector_type(8)));
typedef float floatx4 __attribute__((ext_vector_type(4)));

#define S 256
#define H 512
#define P 32896            // S*(S+1)/2
#define NROWS 65792        // B*P
#define NEGF -1e30f
#define EPSF 1e-12f

// ---------------- ws layout (bytes) ----------------
#define OFF_SEQ    0u          // f32 [B*S*H]
#define OFF_CSUM   1048576u    // f32 [B*S*H]
#define OFF_LN1    2129920u    // f32 [B*S*H]
#define OFF_G1     3178496u    // f32 [B*S*H]
#define OFF_B1     4227072u    // f32 [B*S*H]
#define OFF_WCAT   5275648u    // bf16 [1024*512]
#define OFF_II     6324224u    // u16 [P]
#define OFF_JJ     6390016u    // u16 [P]
#define OFF_MU2    6455808u    // f32 [NROWS]
#define OFF_INV2   6718976u    // f32 [NROWS]
#define OFF_INNER  6982144u    // bf16 [NROWS*H]
// tot (f32 [64*H] = 128 KB) overlays the head of OFF_INNER (consumed by scan2
// before inner_kernel overwrites the region).

// async 16B global->LDS (lane-linear dest: base + lane*16)
__device__ __forceinline__ void gld_lds16(const void* g, void* l) {
    __builtin_amdgcn_global_load_lds(
        (const __attribute__((address_space(1))) void*)g,
        (__attribute__((address_space(3))) void*)l, 16, 0, 0);
}

// ---------------- prep: wcat transpose (blocks 0..1023) + pair tables (1024..) ----------------
// wcatT column (n) order is INTERLEAVED so a 256-col GEMM tile t holds
// G2 cols [t*128, t*128+128) at n = t*256 + 0..127 and the MATCHING B2 cols
// at n = t*256 + 128..255  ->  register-only LN2 epilogue (no LDS exchange).
__global__ __launch_bounds__(512) void prep_kernel(const float* __restrict__ Wg2,
                                                   const float* __restrict__ Wb2,
                                                   bf16* __restrict__ wcatT,
                                                   unsigned short* __restrict__ ii,
                                                   unsigned short* __restrict__ jj) {
    if (blockIdx.x < 1024) {
        int n = blockIdx.x, k = threadIdx.x;
        int tt = n >> 8, c = n & 255;
        int h = tt * 128 + (c & 127);
        float v = (c < 128) ? Wg2[(size_t)k * H + h] : Wb2[(size_t)k * H + h];
        wcatT[(size_t)n * H + k] = __float2bfloat16(v);
    } else {
        int p = (blockIdx.x - 1024) * 512 + threadIdx.x;
        if (p >= P) return;
        float disc = 513.0f * 513.0f - 8.0f * (float)p;
        int i = (int)((513.0f - sqrtf(disc)) * 0.5f);
        i = i < 0 ? 0 : (i > S - 1 ? S - 1 : i);
        while (i > 0 && (i * S - i * (i - 1) / 2) > p) --i;
        while (i < S - 1 && ((i + 1) * S - (i + 1) * i / 2) <= p) ++i;
        int off = i * S - i * (i - 1) / 2;
        ii[p] = (unsigned short)i;
        jj[p] = (unsigned short)(i + (p - off));
    }
}

// ---------------- seq + partial sums + fused LN1 (64 blocks, 8 s-rows each) ----------------
__global__ __launch_bounds__(512) void seq_scan1_ln1(const float* __restrict__ x,
                                                     const float* __restrict__ mask,
                                                     float* __restrict__ seq, float* __restrict__ tot,
                                                     float* __restrict__ ln1) {
    __shared__ float part[8][8][2];
    __shared__ float rstat[8][2];
    int b = blockIdx.x >> 5, sc = blockIdx.x & 31, h = threadIdx.x;
    int wave = h >> 6, lane = h & 63;
    int s0 = sc * 8;
    float v[8];
    float run = 0.0f;
#pragma unroll
    for (int t = 0; t < 8; ++t) {
        int s = s0 + t;
        v[t] = x[(size_t)(b * S + s) * H + h] + (1.0f - mask[b * S + s]) * (-1000.0f);
        seq[(size_t)(b * S + s) * H + h] = v[t];
        run += v[t];
    }
    tot[(size_t)blockIdx.x * H + h] = run;
    // per-row (over h) block stats for LN1
#pragma unroll
    for (int t = 0; t < 8; ++t) {
        float s = v[t], q = v[t] * v[t];
        for (int o = 1; o < 64; o <<= 1) { s += __shfl_xor(s, o); q += __shfl_xor(q, o); }
        if (lane == 0) { part[wave][t][0] = s; part[wave][t][1] = q; }
    }
    __syncthreads();
    if (h < 16) {
        int row = h >> 1, st = h & 1;
        float a = 0.0f;
#pragma unroll
        for (int w = 0; w < 8; ++w) a += part[w][row][st];
        rstat[row][st] = a;
    }
    __syncthreads();
#pragma unroll
    for (int t = 0; t < 8; ++t) {
        float m = rstat[t][0] * (1.0f / 512.0f);
        float var = rstat[t][1] * (1.0f / 512.0f) - m * m;
        var = var < 0.0f ? 0.0f : var;
        float inv = rsqrtf(var + EPSF);
        ln1[(size_t)(b * S + s0 + t) * H + h] = (v[t] - m) * inv;
    }
}

__global__ __launch_bounds__(512) void seq_scan2(const float* __restrict__ seq,
                                                 const float* __restrict__ tot,
                                                 float* __restrict__ csum) {
    int b = blockIdx.x >> 5, sc = blockIdx.x & 31, h = threadIdx.x;
    float run = 0.0f;
    for (int c = 0; c < sc; ++c) run += tot[(size_t)(b * 32 + c) * H + h];
    int s0 = sc * 8;
#pragma unroll
    for (int t = 0; t < 8; ++t) {
        run += seq[(size_t)(b * S + s0 + t) * H + h];
        csum[(size_t)(b * S + s0 + t) * H + h] = run;
    }
}

// ---------------- G1/B1 = bias + seq @ W1 (small f32 GEMM) ----------------
__global__ __launch_bounds__(512) void g1b1_kernel(
    const float* __restrict__ seq, const float* __restrict__ Wg1, const float* __restrict__ Wb1,
    const float* __restrict__ g1, const float* __restrict__ b1,
    float* __restrict__ G1, float* __restrict__ B1) {
    __shared__ float rowbuf[8][H];
    int grp = blockIdx.x;   // 0..63
    int mat = blockIdx.y;   // 0..1
    int h = threadIdx.x;
    int r0 = grp * 8;
    for (int r = 0; r < 8; ++r) rowbuf[r][h] = seq[(size_t)(r0 + r) * H + h];
    __syncthreads();
    const float* W = mat ? Wb1 : Wg1;
    float acc[8] = {0, 0, 0, 0, 0, 0, 0, 0};
#pragma unroll 4
    for (int k = 0; k < H; ++k) {
        float w = W[(size_t)k * H + h];
#pragma unroll
        for (int r = 0; r < 8; ++r) acc[r] += rowbuf[r][k] * w;
    }
    float bias = (mat ? b1 : g1)[h];
    float* dst = mat ? B1 : G1;
    for (int r = 0; r < 8; ++r) dst[(size_t)(r0 + r) * H + h] = acc[r] + bias;
}

// ---------------- inner[p][h] = lam*mean + (1-lam)*max (bf16x2, balanced) ----------------
// j-loop unrolled x4: 8 independent L2 loads in flight per step (breaks the
// load->compute->store latency chain; math order per element unchanged).
__global__ __launch_bounds__(256) void inner_kernel(
    const float* __restrict__ seq, const float* __restrict__ csum,
    const float* __restrict__ lamtha, bf16* __restrict__ inner) {
    int id = blockIdx.x;
    int t = id & 255, b = id >> 8;
    int i = b ? (255 - t) : t;
    int h2 = threadIdx.x;                 // float2 index, 0..255
    float2 lam = ((const float2*)lamtha)[h2];
    float2 oml = {1.0f - lam.x, 1.0f - lam.y};
    const float2* seqb = (const float2*)(seq + (size_t)b * S * H);
    const float2* csb = (const float2*)(csum + (size_t)b * S * H);
    float2 s_i = seqb[i * 256 + h2];
    float2 c_i = csb[i * 256 + h2];
    float2 mrun = {NEGF, NEGF};
    size_t base = (size_t)b * P + (size_t)(i * S - i * (i - 1) / 2);
    __hip_bfloat162* dst = (__hip_bfloat162*)inner;
    int j = i;
#define INNER_STEP(vv, cc, jx)                                             \
    {                                                                      \
        mrun.x = fmaxf(mrun.x, vv.x);                                      \
        mrun.y = fmaxf(mrun.y, vv.y);                                      \
        float rl = 1.0f / (float)((jx) - i + 1);                           \
        float mx = (cc.x - c_i.x + s_i.x) * rl;                            \
        float my = (cc.y - c_i.y + s_i.y) * rl;                            \
        __hip_bfloat162 o;                                                 \
        o.x = __float2bfloat16(lam.x * mx + oml.x * mrun.x);               \
        o.y = __float2bfloat16(lam.y * my + oml.y * mrun.y);               \
        dst[(base + (size_t)((jx) - i)) * 256 + h2] = o;                   \
    }
    for (; j + 4 <= S; j += 4) {
        float2 v0 = seqb[(j + 0) * 256 + h2], c0 = csb[(j + 0) * 256 + h2];
        float2 v1 = seqb[(j + 1) * 256 + h2], c1 = csb[(j + 1) * 256 + h2];
        float2 v2 = seqb[(j + 2) * 256 + h2], c2 = csb[(j + 2) * 256 + h2];
        float2 v3 = seqb[(j + 3) * 256 + h2], c3 = csb[(j + 3) * 256 + h2];
        INNER_STEP(v0, c0, j + 0)
        INNER_STEP(v1, c1, j + 1)
        INNER_STEP(v2, c2, j + 2)
        INNER_STEP(v3, c3, j + 3)
    }
    for (; j < S; ++j) {
        float2 v = seqb[j * 256 + h2];
        float2 c = csb[j * 256 + h2];
        INNER_STEP(v, c, j)
    }
#undef INNER_STEP
}

// ---------------- LN2 row stats: wave per pair-row (float4 loads) ----------------
__global__ void stats_kernel(const float* __restrict__ ln1, const float* __restrict__ G1,
                             const float* __restrict__ B1,
                             const unsigned short* __restrict__ ii,
                             const unsigned short* __restrict__ jj,
                             float* __restrict__ mu2, float* __restrict__ inv2) {
    int r = blockIdx.x * 4 + (threadIdx.x >> 6);
    int lane = threadIdx.x & 63;
    int b = (r >= P) ? 1 : 0;
    int p = r - b * P;
    int i = ii[p], j = jj[p];
    const float4* lp = (const float4*)(ln1 + (size_t)(b * S + j) * H);
    const float4* gp = (const float4*)(G1 + (size_t)(b * S + i) * H);
    const float4* bp = (const float4*)(B1 + (size_t)(b * S + i) * H);
    float sum = 0.0f, ss = 0.0f;
#pragma unroll
    for (int t = 0; t < 2; ++t) {
        int idx = t * 64 + lane;
        float4 a = lp[idx], g = gp[idx], bb = bp[idx];
        float v0 = a.x * g.x + bb.x, v1 = a.y * g.y + bb.y;
        float v2 = a.z * g.z + bb.z, v3 = a.w * g.w + bb.w;
        sum += (v0 + v1) + (v2 + v3);
        ss += (v0 * v0 + v1 * v1) + (v2 * v2 + v3 * v3);
    }
    for (int o = 1; o < 64; o <<= 1) { sum += __shfl_xor(sum, o); ss += __shfl_xor(ss, o); }
    if (lane == 0) {
        float m = sum * (1.0f / 512.0f);
        float var = ss * (1.0f / 512.0f) - m * m;
        var = var < 0.0f ? 0.0f : var;
        mu2[r] = m;
        inv2[r] = rsqrtf(var + EPSF);
    }
}

// ---------------- PERSISTENT fused GEMM (inner @ [Wg2|Wb2]) + LN2 epilogue ----------------
// Grid = 256 blocks (1/CU), 8 waves, 256x256 tile per item.
// Block id = t*64 + g: h-tile t fixed; items rb = g + 64*it (it = 0..3), plus a
// 64-row quarter item of rb=256 for blocks g>=60. id%8 == g%8 -> all 4 t-blocks
// of stream g share one XCD: each A-panel is HBM-fetched once, L2-shared.
// Continuous staging pipeline: bodies kt=6,7 of item i stage kt=0,1 of item i+1,
// so the epilogue (loads + 64 stores/thread, no waits) overlaps the next item's
// in-flight staging, and stores drain (L2 ack) under the next K-loop.
// vmcnt budgets (in-order retirement): steady vmcnt(8) ensures the previous
// body's 8 stages are done while this body's 8 fly; after an epilogue the
// target has 64 stores + 8 stages after it -> vmcnt(63) (safe: 63 <= 72) lets
// all epilogue stores stay outstanding; final drain vmcnt(0).
__global__ __launch_bounds__(512, 2) void gemm_kernel(
    const bf16* __restrict__ inner, const bf16* __restrict__ wcatT,
    const float* __restrict__ g2, const float* __restrict__ b2,
    const float* __restrict__ ln1, const float* __restrict__ G1, const float* __restrict__ B1,
    const unsigned short* __restrict__ ii, const unsigned short* __restrict__ jj,
    const float* __restrict__ mu2, const float* __restrict__ inv2,
    float* __restrict__ out) {
    extern __shared__ __align__(16) char smem[];   // 131072: 2 bufs x (A 32K | B 32K)

    const int tid = threadIdx.x;
    const int wave = tid >> 6, lane = tid & 63;
    const int q = lane >> 4, l15 = lane & 15;
    const int wm = wave & 1, wn = wave >> 1;       // wn 0..3

    const int id = blockIdx.x;
    const int t = id >> 6, g = id & 63;
    const int nit = (g >= 60) ? 5 : 4;

    // staging decomposition: thread -> (row, chunk); source pre-swizzled so the
    // lane-linear LDS write realizes LDS(row, c) = global(row, c ^ (row&7)).
    const int srow = tid >> 3;                    // 0..63
    const int sx8 = ((tid & 7) ^ (srow & 7)) * 8;

    char* const A0 = smem;
    char* const B0 = smem + 32768;
    char* const A1 = smem + 65536;
    char* const B1s = smem + 98304;

    const bf16* const Bp0 = wcatT + (size_t)(t * 256 + srow) * H + sx8;

    float g2v[2], b2v[2];
#pragma unroll
    for (int fg = 0; fg < 2; ++fg) {
        int h = t * 128 + wn * 32 + fg * 16 + l15;
        g2v[fg] = g2[h];
        b2v[fg] = b2[h];
    }

#define STAGE(P0, P1, P2, P3, KT, AD, BD)                                     \
    do {                                                                      \
        gld_lds16((P0) + (KT) * 64, (AD) + 0 * 8192 + wave * 1024);           \
        gld_lds16((P1) + (KT) * 64, (AD) + 1 * 8192 + wave * 1024);           \
        gld_lds16((P2) + (KT) * 64, (AD) + 2 * 8192 + wave * 1024);           \
        gld_lds16((P3) + (KT) * 64, (AD) + 3 * 8192 + wave * 1024);           \
        gld_lds16(Bp0 + (size_t)0 * 64 * H + (KT) * 64, (BD) + 0 * 8192 + wave * 1024); \
        gld_lds16(Bp0 + (size_t)1 * 64 * H + (KT) * 64, (BD) + 1 * 8192 + wave * 1024); \
        gld_lds16(Bp0 + (size_t)2 * 64 * H + (KT) * 64, (BD) + 2 * 8192 + wave * 1024); \
        gld_lds16(Bp0 + (size_t)3 * 64 * H + (KT) * 64, (BD) + 3 * 8192 + wave * 1024); \
    } while (0)

    // A-panel row pointers for an item (rows clamped for the 64-row tail item)
    const bf16 *ApA0, *ApA1, *ApA2, *ApA3, *ApB0, *ApB1, *ApB2, *ApB3;
#define MKAP(R0v, D0, D1, D2, D3)                                             \
    do {                                                                      \
        int r0_ = (R0v) + srow;                                               \
        int ra_ = r0_;             if (ra_ > NROWS - 1) ra_ = NROWS - 1;      \
        int rb_ = r0_ + 64;        if (rb_ > NROWS - 1) rb_ = NROWS - 1;      \
        int rc_ = r0_ + 128;       if (rc_ > NROWS - 1) rc_ = NROWS - 1;      \
        int rd_ = r0_ + 192;       if (rd_ > NROWS - 1) rd_ = NROWS - 1;      \
        D0 = inner + (size_t)ra_ * H + sx8;                                   \
        D1 = inner + (size_t)rb_ * H + sx8;                                   \
        D2 = inner + (size_t)rc_ * H + sx8;                                   \
        D3 = inner + (size_t)rd_ * H + sx8;                                   \
    } while (0)

    // prologue: stage item 0 kt=0,1 into both buffers; wait only the first.
    MKAP(g * 256, ApA0, ApA1, ApA2, ApA3);
    STAGE(ApA0, ApA1, ApA2, ApA3, 0, A0, B0);
    STAGE(ApA0, ApA1, ApA2, ApA3, 1, A1, B1s);
    asm volatile("s_waitcnt vmcnt(8)" ::: "memory");
    asm volatile("s_barrier" ::: "memory");

    floatx4 acc[8][4];

    for (int it = 0; it < nit; ++it) {
        const int R0 = (it < 4) ? (g * 256 + it * 16384) : (65536 + (g - 60) * 64);
        const int mrows = (it < 4) ? 256 : 64;
        {
            int itn = (it + 1 < nit) ? it + 1 : it;
            int R0n = (itn < 4) ? (g * 256 + itn * 16384) : (65536 + (g - 60) * 64);
            MKAP(R0n, ApB0, ApB1, ApB2, ApB3);
        }
#pragma unroll
        for (int a = 0; a < 8; ++a)
#pragma unroll
            for (int c = 0; c < 4; ++c) acc[a][c] = (floatx4){0.f, 0.f, 0.f, 0.f};

#pragma unroll
        for (int kt = 0; kt < 8; ++kt) {
            char* const As = (kt & 1) ? A1 : A0;
            char* const Bs = (kt & 1) ? B1s : B0;

            short8 bfr[4][2], af[8][2];
#pragma unroll
            for (int ks = 0; ks < 2; ++ks) {
#pragma unroll
                for (int fn = 0; fn < 4; ++fn) {
                    int nr = (fn < 2 ? wn * 32 + fn * 16 : 128 + wn * 32 + (fn - 2) * 16) + l15;
                    bfr[fn][ks] = *(const short8*)(Bs + nr * 128 + (((ks * 4 + q) ^ (l15 & 7)) << 4));
                }
#pragma unroll
                for (int fm = 0; fm < 8; ++fm) {
                    int mr = wm * 128 + fm * 16 + l15;
                    af[fm][ks] = *(const short8*)(As + mr * 128 + (((ks * 4 + q) ^ (l15 & 7)) << 4));
                }
            }

            __builtin_amdgcn_s_setprio(1);
#pragma unroll
            for (int fm = 0; fm < 8; ++fm)
#pragma unroll
                for (int fn = 0; fn < 4; ++fn)
                    acc[fm][fn] = __builtin_amdgcn_mfma_f32_16x16x32_bf16(af[fm][0], bfr[fn][0], acc[fm][fn], 0, 0, 0);
            __builtin_amdgcn_s_setprio(0);

            // all my LDS reads retired -> barrier -> this buffer is dead, refill
            asm volatile("s_waitcnt lgkmcnt(0)" ::: "memory");
            asm volatile("s_barrier" ::: "memory");
            if (kt < 6) {
                STAGE(ApA0, ApA1, ApA2, ApA3, kt + 2, As, Bs);
            } else if (it + 1 < nit) {
                STAGE(ApB0, ApB1, ApB2, ApB3, kt - 6, As, Bs);
            }

            __builtin_amdgcn_s_setprio(1);
#pragma unroll
            for (int fm = 0; fm < 8; ++fm)
#pragma unroll
                for (int fn = 0; fn < 4; ++fn)
                    acc[fm][fn] = __builtin_amdgcn_mfma_f32_16x16x32_bf16(af[fm][1], bfr[fn][1], acc[fm][fn], 0, 0, 0);
            __builtin_amdgcn_s_setprio(0);

            // end-of-body wait: ensure the PREVIOUS body's 8 stages landed.
            if (it == nit - 1 && kt >= 6) {
                if (kt == 6) {   // previous body staged; nothing issued after -> full drain
                    asm volatile("s_waitcnt vmcnt(0)" ::: "memory");
                    asm volatile("s_barrier" ::: "memory");
                }
                // kt == 7: last body; no further buffer reads -> no wait/barrier.
            } else {
                if (kt == 0 && it > 0) {
                    // target has 64 epilogue stores + 8 stages after it (72):
                    // vmcnt(63) is safe and tolerates all stores in flight.
                    asm volatile("s_waitcnt vmcnt(63)" ::: "memory");
                } else {
                    asm volatile("s_waitcnt vmcnt(8)" ::: "memory");
                }
                asm volatile("s_barrier" ::: "memory");
            }
        }

        // ---- register-only LN2 epilogue (no LDS, no barriers, no store waits) ----
#pragma unroll
        for (int fm = 0; fm < 8; ++fm) {
#pragma unroll
            for (int r = 0; r < 4; ++r) {
                int m = wm * 128 + fm * 16 + q * 4 + r;
                int rg = R0 + m;
                int rgc = rg < NROWS ? rg : NROWS - 1;
                int b = (rgc >= P) ? 1 : 0;
                int p = rgc - b * P;
                int i = ii[p], j = jj[p];
                float mu = mu2[rgc], iv = inv2[rgc];
                const float* lp = ln1 + (size_t)(b * S + j) * H + t * 128 + wn * 32;
                const float* gp = G1 + (size_t)(b * S + i) * H + t * 128 + wn * 32;
                const float* bp = B1 + (size_t)(b * S + i) * H + t * 128 + wn * 32;
                float* op = out + (size_t)rg * H + t * 128 + wn * 32;
                float res[2];
#pragma unroll
                for (int fg = 0; fg < 2; ++fg) {
                    int c = fg * 16 + l15;
                    float s = (lp[c] * gp[c] + bp[c] - mu) * iv;
                    float G2v = acc[fm][fg][r] + g2v[fg];
                    float B2v = acc[fm][fg + 2][r] + b2v[fg];
                    res[fg] = s * G2v + B2v;
                }
                if (m < mrows) {
                    op[0 * 16 + l15] = res[0];
                    op[1 * 16 + l15] = res[1];
                }
            }
        }

        ApA0 = ApB0; ApA1 = ApB1; ApA2 = ApB2; ApA3 = ApB3;
    }
#undef STAGE
#undef MKAP
}

// ---------------- launcher ----------------
extern "C" void kernel_launch(void* const* d_in, const int* in_sizes, int n_in,
                              void* d_out, int out_size, void* d_ws, size_t ws_size,
                              hipStream_t stream) {
    const float* x = (const float*)d_in[0];
    const float* mask = (const float*)d_in[1];
    const float* lamtha = (const float*)d_in[2];
    const float* Wg1 = (const float*)d_in[3];
    const float* Wb1 = (const float*)d_in[4];
    const float* g1 = (const float*)d_in[5];
    const float* b1 = (const float*)d_in[6];
    const float* Wg2 = (const float*)d_in[7];
    const float* Wb2 = (const float*)d_in[8];
    const float* g2 = (const float*)d_in[9];
    const float* b2 = (const float*)d_in[10];
    float* out = (float*)d_out;

    char* ws = (char*)d_ws;
    float* seq = (float*)(ws + OFF_SEQ);
    float* csum = (float*)(ws + OFF_CSUM);
    float* ln1 = (float*)(ws + OFF_LN1);
    float* G1 = (float*)(ws + OFF_G1);
    float* B1 = (float*)(ws + OFF_B1);
    bf16* wcatT = (bf16*)(ws + OFF_WCAT);
    unsigned short* iiA = (unsigned short*)(ws + OFF_II);
    unsigned short* jjA = (unsigned short*)(ws + OFF_JJ);
    float* mu2 = (float*)(ws + OFF_MU2);
    float* inv2 = (float*)(ws + OFF_INV2);
    bf16* inner = (bf16*)(ws + OFF_INNER);
    float* tot = (float*)(ws + OFF_INNER);   // overlay; consumed before inner is written

    static bool attr_set = false;
    if (!attr_set) {
        hipFuncSetAttribute((const void*)gemm_kernel,
                            hipFuncAttributeMaxDynamicSharedMemorySize, 131072);
        attr_set = true;
    }

    hipLaunchKernelGGL(prep_kernel, dim3(1089), dim3(512), 0, stream, Wg2, Wb2, wcatT, iiA, jjA);
    hipLaunchKernelGGL(seq_scan1_ln1, dim3(64), dim3(512), 0, stream, x, mask, seq, tot, ln1);
    hipLaunchKernelGGL(seq_scan2, dim3(64), dim3(512), 0, stream, seq, tot, csum);
    hipLaunchKernelGGL(g1b1_kernel, dim3(64, 2), dim3(512), 0, stream, seq, Wg1, Wb1, g1, b1, G1, B1);
    hipLaunchKernelGGL(inner_kernel, dim3(512), dim3(256), 0, stream, seq, csum, lamtha, inner);
    hipLaunchKernelGGL(stats_kernel, dim3(16448), dim3(256), 0, stream, ln1, G1, B1, iiA, jjA, mu2, inv2);
    hipLaunchKernelGGL(gemm_kernel, dim3(256), dim3(512), 131072, stream,
                       inner, wcatT, g2, b2, ln1, G1, B1, iiA, jjA, mu2, inv2, out);
}

// Round 3
// 313.406 us; speedup vs baseline: 1.9252x; 1.9252x over previous
//
#include <hip/hip_runtime.h>
#include <hip/hip_bf16.h>

typedef __hip_bfloat16 bf16;
typedef short short8 __attribute__((ext_vector_type(8)));
typedef float floatx4 __attribute__((ext_vector_type(4)));

#define S 256
#define H 512
#define P 32896            // S*(S+1)/2
#define NROWS 65792        // B*P
#define NEGF -1e30f
#define EPSF 1e-12f

// ---------------- ws layout (bytes) ----------------
#define OFF_SEQ    0u          // f32 [B*S*H]
#define OFF_CSUM   1048576u    // f32 [B*S*H]
#define OFF_LN1    2129920u    // f32 [B*S*H]
#define OFF_G1     3178496u    // f32 [B*S*H]
#define OFF_B1     4227072u    // f32 [B*S*H]
#define OFF_WCAT   5275648u    // bf16 [1024*512]
#define OFF_II     6324224u    // u16 [P]
#define OFF_JJ     6390016u    // u16 [P]
#define OFF_MU2    6455808u    // f32 [NROWS]
#define OFF_INV2   6718976u    // f32 [NROWS]
#define OFF_INNER  6982144u    // bf16 [NROWS*H]
// tot (f32 [64*H] = 128 KB) overlays the head of OFF_INNER (consumed by scan2
// before inner_kernel overwrites the region).

// async 16B global->LDS (lane-linear dest: base + lane*16)
__device__ __forceinline__ void gld_lds16(const void* g, void* l) {
    __builtin_amdgcn_global_load_lds(
        (const __attribute__((address_space(1))) void*)g,
        (__attribute__((address_space(3))) void*)l, 16, 0, 0);
}

// ---------------- prep: wcat transpose (blocks 0..1023) + pair tables (1024..) ----------------
// wcatT row (n) order interleaved at 64-col granularity: GEMM htile t
// (wcatT rows [t*128, t*128+128)) holds G2 cols [t*64, t*64+64) at local rows
// 0..63 and the MATCHING B2 cols at local rows 64..127 -> register-only LN2
// epilogue (each wave owns matching G2/B2 fragments).
__global__ __launch_bounds__(512) void prep_kernel(const float* __restrict__ Wg2,
                                                   const float* __restrict__ Wb2,
                                                   bf16* __restrict__ wcatT,
                                                   unsigned short* __restrict__ ii,
                                                   unsigned short* __restrict__ jj) {
    if (blockIdx.x < 1024) {
        int n = blockIdx.x, k = threadIdx.x;
        int tt = n >> 7, c = n & 127;
        int h = tt * 64 + (c & 63);
        float v = (c < 64) ? Wg2[(size_t)k * H + h] : Wb2[(size_t)k * H + h];
        wcatT[(size_t)n * H + k] = __float2bfloat16(v);
    } else {
        int p = (blockIdx.x - 1024) * 512 + threadIdx.x;
        if (p >= P) return;
        float disc = 513.0f * 513.0f - 8.0f * (float)p;
        int i = (int)((513.0f - sqrtf(disc)) * 0.5f);
        i = i < 0 ? 0 : (i > S - 1 ? S - 1 : i);
        while (i > 0 && (i * S - i * (i - 1) / 2) > p) --i;
        while (i < S - 1 && ((i + 1) * S - (i + 1) * i / 2) <= p) ++i;
        int off = i * S - i * (i - 1) / 2;
        ii[p] = (unsigned short)i;
        jj[p] = (unsigned short)(i + (p - off));
    }
}

// ---------------- seq + partial sums + fused LN1 (64 blocks, 8 s-rows each) ----------------
__global__ __launch_bounds__(512) void seq_scan1_ln1(const float* __restrict__ x,
                                                     const float* __restrict__ mask,
                                                     float* __restrict__ seq, float* __restrict__ tot,
                                                     float* __restrict__ ln1) {
    __shared__ float part[8][8][2];
    __shared__ float rstat[8][2];
    int b = blockIdx.x >> 5, sc = blockIdx.x & 31, h = threadIdx.x;
    int wave = h >> 6, lane = h & 63;
    int s0 = sc * 8;
    float v[8];
    float run = 0.0f;
#pragma unroll
    for (int t = 0; t < 8; ++t) {
        int s = s0 + t;
        v[t] = x[(size_t)(b * S + s) * H + h] + (1.0f - mask[b * S + s]) * (-1000.0f);
        seq[(size_t)(b * S + s) * H + h] = v[t];
        run += v[t];
    }
    tot[(size_t)blockIdx.x * H + h] = run;
#pragma unroll
    for (int t = 0; t < 8; ++t) {
        float s = v[t], q = v[t] * v[t];
        for (int o = 1; o < 64; o <<= 1) { s += __shfl_xor(s, o); q += __shfl_xor(q, o); }
        if (lane == 0) { part[wave][t][0] = s; part[wave][t][1] = q; }
    }
    __syncthreads();
    if (h < 16) {
        int row = h >> 1, st = h & 1;
        float a = 0.0f;
#pragma unroll
        for (int w = 0; w < 8; ++w) a += part[w][row][st];
        rstat[row][st] = a;
    }
    __syncthreads();
#pragma unroll
    for (int t = 0; t < 8; ++t) {
        float m = rstat[t][0] * (1.0f / 512.0f);
        float var = rstat[t][1] * (1.0f / 512.0f) - m * m;
        var = var < 0.0f ? 0.0f : var;
        float inv = rsqrtf(var + EPSF);
        ln1[(size_t)(b * S + s0 + t) * H + h] = (v[t] - m) * inv;
    }
}

__global__ __launch_bounds__(512) void seq_scan2(const float* __restrict__ seq,
                                                 const float* __restrict__ tot,
                                                 float* __restrict__ csum) {
    int b = blockIdx.x >> 5, sc = blockIdx.x & 31, h = threadIdx.x;
    float run = 0.0f;
    for (int c = 0; c < sc; ++c) run += tot[(size_t)(b * 32 + c) * H + h];
    int s0 = sc * 8;
#pragma unroll
    for (int t = 0; t < 8; ++t) {
        run += seq[(size_t)(b * S + s0 + t) * H + h];
        csum[(size_t)(b * S + s0 + t) * H + h] = run;
    }
}

// ---------------- G1/B1 = bias + seq @ W1 (small f32 GEMM) ----------------
// 256 blocks (full GPU): 4 rows per block, grid (128, 2).
__global__ __launch_bounds__(512) void g1b1_kernel(
    const float* __restrict__ seq, const float* __restrict__ Wg1, const float* __restrict__ Wb1,
    const float* __restrict__ g1, const float* __restrict__ b1,
    float* __restrict__ G1, float* __restrict__ B1) {
    __shared__ float rowbuf[4][H];
    int grp = blockIdx.x;   // 0..127
    int mat = blockIdx.y;   // 0..1
    int h = threadIdx.x;
    int r0 = grp * 4;
    for (int r = 0; r < 4; ++r) rowbuf[r][h] = seq[(size_t)(r0 + r) * H + h];
    __syncthreads();
    const float* W = mat ? Wb1 : Wg1;
    float acc[4] = {0, 0, 0, 0};
#pragma unroll 8
    for (int k = 0; k < H; ++k) {
        float w = W[(size_t)k * H + h];
#pragma unroll
        for (int r = 0; r < 4; ++r) acc[r] += rowbuf[r][k] * w;
    }
    float bias = (mat ? b1 : g1)[h];
    float* dst = mat ? B1 : G1;
    for (int r = 0; r < 4; ++r) dst[(size_t)(r0 + r) * H + h] = acc[r] + bias;
}

// ---------------- inner[p][h] = lam*mean + (1-lam)*max (bf16x2, balanced) ----------------
// j-loop unrolled x4: 8 independent L2 loads in flight per step.
__global__ __launch_bounds__(256) void inner_kernel(
    const float* __restrict__ seq, const float* __restrict__ csum,
    const float* __restrict__ lamtha, bf16* __restrict__ inner) {
    int id = blockIdx.x;
    int t = id & 255, b = id >> 8;
    int i = b ? (255 - t) : t;
    int h2 = threadIdx.x;                 // float2 index, 0..255
    float2 lam = ((const float2*)lamtha)[h2];
    float2 oml = {1.0f - lam.x, 1.0f - lam.y};
    const float2* seqb = (const float2*)(seq + (size_t)b * S * H);
    const float2* csb = (const float2*)(csum + (size_t)b * S * H);
    float2 s_i = seqb[i * 256 + h2];
    float2 c_i = csb[i * 256 + h2];
    float2 mrun = {NEGF, NEGF};
    size_t base = (size_t)b * P + (size_t)(i * S - i * (i - 1) / 2);
    __hip_bfloat162* dst = (__hip_bfloat162*)inner;
    int j = i;
#define INNER_STEP(vv, cc, jx)                                             \
    {                                                                      \
        mrun.x = fmaxf(mrun.x, vv.x);                                      \
        mrun.y = fmaxf(mrun.y, vv.y);                                      \
        float rl = 1.0f / (float)((jx) - i + 1);                           \
        float mx = (cc.x - c_i.x + s_i.x) * rl;                            \
        float my = (cc.y - c_i.y + s_i.y) * rl;                            \
        __hip_bfloat162 o;                                                 \
        o.x = __float2bfloat16(lam.x * mx + oml.x * mrun.x);               \
        o.y = __float2bfloat16(lam.y * my + oml.y * mrun.y);               \
        dst[(base + (size_t)((jx) - i)) * 256 + h2] = o;                   \
    }
    for (; j + 4 <= S; j += 4) {
        float2 v0 = seqb[(j + 0) * 256 + h2], c0 = csb[(j + 0) * 256 + h2];
        float2 v1 = seqb[(j + 1) * 256 + h2], c1 = csb[(j + 1) * 256 + h2];
        float2 v2 = seqb[(j + 2) * 256 + h2], c2 = csb[(j + 2) * 256 + h2];
        float2 v3 = seqb[(j + 3) * 256 + h2], c3 = csb[(j + 3) * 256 + h2];
        INNER_STEP(v0, c0, j + 0)
        INNER_STEP(v1, c1, j + 1)
        INNER_STEP(v2, c2, j + 2)
        INNER_STEP(v3, c3, j + 3)
    }
    for (; j < S; ++j) {
        float2 v = seqb[j * 256 + h2];
        float2 c = csb[j * 256 + h2];
        INNER_STEP(v, c, j)
    }
#undef INNER_STEP
}

// ---------------- LN2 row stats: wave per pair-row (float4 loads) ----------------
__global__ void stats_kernel(const float* __restrict__ ln1, const float* __restrict__ G1,
                             const float* __restrict__ B1,
                             const unsigned short* __restrict__ ii,
                             const unsigned short* __restrict__ jj,
                             float* __restrict__ mu2, float* __restrict__ inv2) {
    int r = blockIdx.x * 4 + (threadIdx.x >> 6);
    int lane = threadIdx.x & 63;
    int b = (r >= P) ? 1 : 0;
    int p = r - b * P;
    int i = ii[p], j = jj[p];
    const float4* lp = (const float4*)(ln1 + (size_t)(b * S + j) * H);
    const float4* gp = (const float4*)(G1 + (size_t)(b * S + i) * H);
    const float4* bp = (const float4*)(B1 + (size_t)(b * S + i) * H);
    float sum = 0.0f, ss = 0.0f;
#pragma unroll
    for (int t = 0; t < 2; ++t) {
        int idx = t * 64 + lane;
        float4 a = lp[idx], g = gp[idx], bb = bp[idx];
        float v0 = a.x * g.x + bb.x, v1 = a.y * g.y + bb.y;
        float v2 = a.z * g.z + bb.z, v3 = a.w * g.w + bb.w;
        sum += (v0 + v1) + (v2 + v3);
        ss += (v0 * v0 + v1 * v1) + (v2 * v2 + v3 * v3);
    }
    for (int o = 1; o < 64; o <<= 1) { sum += __shfl_xor(sum, o); ss += __shfl_xor(ss, o); }
    if (lane == 0) {
        float m = sum * (1.0f / 512.0f);
        float var = ss * (1.0f / 512.0f) - m * m;
        var = var < 0.0f ? 0.0f : var;
        mu2[r] = m;
        inv2[r] = rsqrtf(var + EPSF);
    }
}

// ---------------- fused GEMM (inner @ [Wg2|Wb2]) + LN2 epilogue ----------------
// 128x128 tile, 4 waves (2M x 2N), BK=64, LDS double-buffered (64 KB)
// -> 2 blocks/CU: block A's epilogue/stalls overlap block B's K-loop.
// K-loop pipeline/waits/swizzle identical to the proven 256x256 version
// (stage kt+2 after lgkmcnt(0)+barrier; steady vmcnt(8); never 0 mid-loop).
// Each wave holds matching G2 (fn 0..1) and B2 (fn 2..3) columns for the SAME
// h-range -> register-only LN2 epilogue, no LDS exchange, no end barriers.
// Grid 4112 = 514 row-panels x 8 htiles; decode keeps the 8 htiles of a panel
// on ONE XCD within a 64-id window (A-panel fetched from HBM once, L2-shared).
__global__ __launch_bounds__(256, 2) void gemm_kernel(
    const bf16* __restrict__ inner, const bf16* __restrict__ wcatT,
    const float* __restrict__ g2, const float* __restrict__ b2,
    const float* __restrict__ ln1, const float* __restrict__ G1, const float* __restrict__ B1,
    const unsigned short* __restrict__ ii, const unsigned short* __restrict__ jj,
    const float* __restrict__ mu2, const float* __restrict__ inv2,
    float* __restrict__ out) {
    extern __shared__ __align__(16) char smem[];   // 65536: 2 bufs x (A 16K | B 16K)

    const int tid = threadIdx.x;
    const int wave = tid >> 6, lane = tid & 63;
    const int q = lane >> 4, l15 = lane & 15;
    const int wm = wave & 1, wn = wave >> 1;       // wm 0..1, wn 0..1

    // XCD-aware decode: super-tiles of 8 row-panels x 8 htiles
    const int id = blockIdx.x;
    int rb, t;
    if (id < 4096) { rb = (id >> 6) * 8 + (id & 7); t = (id >> 3) & 7; }
    else           { int w = id - 4096; rb = 512 + (w & 1); t = w >> 1; }
    const int R0 = rb * 128;

    // staging decomposition: thread -> (row, chunk); source pre-swizzled so the
    // lane-linear LDS write realizes LDS(row, c) = global(row, c ^ (row&7)).
    const int srow = tid >> 3;                    // 0..31
    const int sx8 = ((tid & 7) ^ (srow & 7)) * 8;
    const bf16* const Ag = inner + (size_t)(R0 + srow) * H + sx8;
    const bf16* const Bg = wcatT + (size_t)(t * 128 + srow) * H + sx8;

    char* const A0 = smem;
    char* const B0 = smem + 16384;
    char* const A1 = smem + 32768;
    char* const B1s = smem + 49152;

    floatx4 acc[4][4];
#pragma unroll
    for (int a = 0; a < 4; ++a)
#pragma unroll
        for (int c = 0; c < 4; ++c) acc[a][c] = (floatx4){0.f, 0.f, 0.f, 0.f};

    auto STAGE = [&](int kt, char* Ad, char* Bd) {
#pragma unroll
        for (int i2 = 0; i2 < 4; ++i2)
            gld_lds16(Ag + (size_t)i2 * 32 * H + kt * 64, Ad + i2 * 4096 + wave * 1024);
#pragma unroll
        for (int i2 = 0; i2 < 4; ++i2)
            gld_lds16(Bg + (size_t)i2 * 32 * H + kt * 64, Bd + i2 * 4096 + wave * 1024);
    };

    // prologue: fill both buffers; wait only the first (8 loads stay in flight)
    STAGE(0, A0, B0);
    STAGE(1, A1, B1s);
    asm volatile("s_waitcnt vmcnt(8)" ::: "memory");
    asm volatile("s_barrier" ::: "memory");

#pragma unroll
    for (int kt = 0; kt < 8; ++kt) {
        char* const As = (kt & 1) ? A1 : A0;
        char* const Bs = (kt & 1) ? B1s : B0;

        short8 bfr[4][2], af[4][2];
#pragma unroll
        for (int ks = 0; ks < 2; ++ks) {
#pragma unroll
            for (int fn = 0; fn < 4; ++fn) {
                int nr = (fn < 2 ? wn * 32 + fn * 16 : 64 + wn * 32 + (fn - 2) * 16) + l15;
                bfr[fn][ks] = *(const short8*)(Bs + nr * 128 + (((ks * 4 + q) ^ (l15 & 7)) << 4));
            }
#pragma unroll
            for (int fm = 0; fm < 4; ++fm) {
                int mr = wm * 64 + fm * 16 + l15;
                af[fm][ks] = *(const short8*)(As + mr * 128 + (((ks * 4 + q) ^ (l15 & 7)) << 4));
            }
        }

        __builtin_amdgcn_s_setprio(1);
#pragma unroll
        for (int fm = 0; fm < 4; ++fm)
#pragma unroll
            for (int fn = 0; fn < 4; ++fn)
                acc[fm][fn] = __builtin_amdgcn_mfma_f32_16x16x32_bf16(af[fm][0], bfr[fn][0], acc[fm][fn], 0, 0, 0);
        __builtin_amdgcn_s_setprio(0);

        if (kt < 6) {
            // all my LDS reads done -> barrier -> buffer is dead, refill with kt+2
            asm volatile("s_waitcnt lgkmcnt(0)" ::: "memory");
            asm volatile("s_barrier" ::: "memory");
            STAGE(kt + 2, As, Bs);
        }

        __builtin_amdgcn_s_setprio(1);
#pragma unroll
        for (int fm = 0; fm < 4; ++fm)
#pragma unroll
            for (int fn = 0; fn < 4; ++fn)
                acc[fm][fn] = __builtin_amdgcn_mfma_f32_16x16x32_bf16(af[fm][1], bfr[fn][1], acc[fm][fn], 0, 0, 0);
        __builtin_amdgcn_s_setprio(0);

        if (kt < 6) {
            // wait kt+1's 8 loads (kt+2's 8 remain in flight across the barrier)
            asm volatile("s_waitcnt vmcnt(8)" ::: "memory");
            asm volatile("s_barrier" ::: "memory");
        } else if (kt == 6) {
            asm volatile("s_waitcnt vmcnt(0)" ::: "memory");
            asm volatile("s_barrier" ::: "memory");
        }
    }

    // ---- register-only LN2 epilogue (all 4 waves, no LDS, no barriers) ----
    float g2v[2], b2v[2];
#pragma unroll
    for (int fg = 0; fg < 2; ++fg) {
        int h = t * 64 + wn * 32 + fg * 16 + l15;
        g2v[fg] = g2[h];
        b2v[fg] = b2[h];
    }
#pragma unroll
    for (int fm = 0; fm < 4; ++fm) {
#pragma unroll
        for (int r = 0; r < 4; ++r) {
            int m = wm * 64 + fm * 16 + q * 4 + r;
            int rg = R0 + m;
            int b = (rg >= P) ? 1 : 0;
            int p = rg - b * P;
            int i = ii[p], j = jj[p];
            float mu = mu2[rg], iv = inv2[rg];
            const float* lp = ln1 + (size_t)(b * S + j) * H + t * 64 + wn * 32;
            const float* gp = G1 + (size_t)(b * S + i) * H + t * 64 + wn * 32;
            const float* bp = B1 + (size_t)(b * S + i) * H + t * 64 + wn * 32;
            float* op = out + (size_t)rg * H + t * 64 + wn * 32;
#pragma unroll
            for (int fg = 0; fg < 2; ++fg) {
                int c = fg * 16 + l15;
                float s = (lp[c] * gp[c] + bp[c] - mu) * iv;
                float G2v = acc[fm][fg][r] + g2v[fg];
                float B2v = acc[fm][fg + 2][r] + b2v[fg];
                op[c] = s * G2v + B2v;
            }
        }
    }
}

// ---------------- launcher ----------------
extern "C" void kernel_launch(void* const* d_in, const int* in_sizes, int n_in,
                              void* d_out, int out_size, void* d_ws, size_t ws_size,
                              hipStream_t stream) {
    const float* x = (const float*)d_in[0];
    const float* mask = (const float*)d_in[1];
    const float* lamtha = (const float*)d_in[2];
    const float* Wg1 = (const float*)d_in[3];
    const float* Wb1 = (const float*)d_in[4];
    const float* g1 = (const float*)d_in[5];
    const float* b1 = (const float*)d_in[6];
    const float* Wg2 = (const float*)d_in[7];
    const float* Wb2 = (const float*)d_in[8];
    const float* g2 = (const float*)d_in[9];
    const float* b2 = (const float*)d_in[10];
    float* out = (float*)d_out;

    char* ws = (char*)d_ws;
    float* seq = (float*)(ws + OFF_SEQ);
    float* csum = (float*)(ws + OFF_CSUM);
    float* ln1 = (float*)(ws + OFF_LN1);
    float* G1 = (float*)(ws + OFF_G1);
    float* B1 = (float*)(ws + OFF_B1);
    bf16* wcatT = (bf16*)(ws + OFF_WCAT);
    unsigned short* iiA = (unsigned short*)(ws + OFF_II);
    unsigned short* jjA = (unsigned short*)(ws + OFF_JJ);
    float* mu2 = (float*)(ws + OFF_MU2);
    float* inv2 = (float*)(ws + OFF_INV2);
    bf16* inner = (bf16*)(ws + OFF_INNER);
    float* tot = (float*)(ws + OFF_INNER);   // overlay; consumed before inner is written

    static bool attr_set = false;
    if (!attr_set) {
        hipFuncSetAttribute((const void*)gemm_kernel,
                            hipFuncAttributeMaxDynamicSharedMemorySize, 65536);
        attr_set = true;
    }

    hipLaunchKernelGGL(prep_kernel, dim3(1089), dim3(512), 0, stream, Wg2, Wb2, wcatT, iiA, jjA);
    hipLaunchKernelGGL(seq_scan1_ln1, dim3(64), dim3(512), 0, stream, x, mask, seq, tot, ln1);
    hipLaunchKernelGGL(seq_scan2, dim3(64), dim3(512), 0, stream, seq, tot, csum);
    hipLaunchKernelGGL(g1b1_kernel, dim3(128, 2), dim3(512), 0, stream, seq, Wg1, Wb1, g1, b1, G1, B1);
    hipLaunchKernelGGL(inner_kernel, dim3(512), dim3(256), 0, stream, seq, csum, lamtha, inner);
    hipLaunchKernelGGL(stats_kernel, dim3(16448), dim3(256), 0, stream, ln1, G1, B1, iiA, jjA, mu2, inv2);
    hipLaunchKernelGGL(gemm_kernel, dim3(4112), dim3(256), 65536, stream,
                       inner, wcatT, g2, b2, ln1, G1, B1, iiA, jjA, mu2, inv2, out);
}